// Round 3
// baseline (160.416 us; speedup 1.0000x reference)
//
#include <hip/hip_runtime.h>
#include <hip/hip_fp16.h>

typedef _Float16 half8 __attribute__((ext_vector_type(8)));
typedef __attribute__((ext_vector_type(4))) float f32x4;

#define N_VEC 32768
#define OUT_ELEMS 8388608

// ws layout (bytes):
// 0       counts int[1024]            (zeroed)
// 4096    loss   float                (zeroed)
// 4100    ticket int                  (zeroed)
// 8192    sq     float[1024]
// 16384   chs    ushort[1024*256]     (fp16 of 1024*cb)
// 540672  partv  float[2*32768]
// 802816  partk  int[2*32768]
// 1064960 xsq    float[32768]
// 1196032 codeG  int[32768]

// ---- prep: codebook -> fp16 (scaled by 1024, exact pow2) + ||c||^2 ----
__global__ __launch_bounds__(256) void prep_kernel(const float* __restrict__ cb,
        unsigned short* __restrict__ chs, float* __restrict__ sq) {
    const int t = threadIdx.x;
    const int row = blockIdx.x * 16 + (t >> 4);
    const int d0 = (t & 15) * 16;
    const float* src = cb + row * 256 + d0;
    half8 h0, h1;
    float s = 0.f;
#pragma unroll
    for (int i = 0; i < 16; ++i) {
        const float v = src[i];
        s += v * v;
        const _Float16 h = (_Float16)(v * 1024.f);   // *1024 exact; fp16 round ~2^-12 rel
        if (i < 8) h0[i] = h; else h1[i - 8] = h;
    }
    *(half8*)(chs + row * 256 + d0) = h0;
    *(half8*)(chs + row * 256 + d0 + 8) = h1;
#pragma unroll
    for (int off = 1; off < 16; off <<= 1) s += __shfl_xor(s, off);
    if ((t & 15) == 0) sq[row] = s;
}

// ---- argmin: fp16 MFMA, 1 term. grid 512 = 256 rowgroups x 2 halves; 4 waves/blk ----
__global__ __launch_bounds__(256, 2) void argmin_mfma_kernel(
    const float* __restrict__ x, const unsigned short* __restrict__ chs,
    const float* __restrict__ sq,
    float* __restrict__ partv, int* __restrict__ partk, float* __restrict__ xsq_out)
{
    __shared__ unsigned short Bs[2][16][264];   // fp16 B tile, dbuf
    const int t = threadIdx.x;
    const int lane = t & 63;
    const int w = t >> 6;                       // wave 0..3
    const int m = lane & 15;
    const int q = lane >> 4;
    const int half = blockIdx.x & 1;
    const int rg = blockIdx.x >> 1;             // 0..255
    const int kb = half * 512;
    const int row0 = rg * 128 + w * 32;
    const float* xb = x + (size_t)(row0 >> 10) * (256 * 1024);
    const int hwb = row0 & 1023;

    // A prologue: strided loads -> fp16 frags (A[m][k], k = q*8+j within 32-chunk)
    half8 Ah[2][8];
#pragma unroll
    for (int f = 0; f < 2; ++f) {
        const int hw = hwb + f * 16 + m;
        float xs = 0.f;
#pragma unroll
        for (int ks = 0; ks < 8; ++ks) {
            half8 a;
#pragma unroll
            for (int j = 0; j < 8; ++j) {
                const float v = xb[(size_t)(ks * 32 + q * 8 + j) * 1024 + hw];
                xs += v * v;
                a[j] = (_Float16)v;
            }
            Ah[f][ks] = a;
        }
        xs += __shfl_xor(xs, 16);
        xs += __shfl_xor(xs, 32);
        if (q == 0 && half == 0) xsq_out[row0 + f * 16 + m] = xs;
    }

    // B staging: tile = 16 codes x 256 d fp16 = 8 KB; 256 thr x 32 B
    const int sc = t >> 4;    // code 0..15
    const int sk = t & 15;    // chunk 0..15 (of 32)
    const unsigned short* gh = chs + ((size_t)kb << 8);
    {
        const size_t o = ((size_t)sc << 8) + sk * 8;
        *(half8*)&Bs[0][sc][sk * 8]       = *(const half8*)(gh + o);
        *(half8*)&Bs[0][sc][sk * 8 + 128] = *(const half8*)(gh + o + 128);
    }

    float bestv[2][4];
    int   bestk[2][4];
#pragma unroll
    for (int f = 0; f < 2; ++f)
#pragma unroll
        for (int r = 0; r < 4; ++r) { bestv[f][r] = 3.4e38f; bestk[f][r] = 0; }

    for (int tile = 0; tile < 32; ++tile) {
        const int buf = tile & 1;
        half8 n0, n1;
        if (tile + 1 < 32) {
            const size_t o = ((size_t)((tile + 1) * 16 + sc) << 8) + sk * 8;
            n0 = *(const half8*)(gh + o);
            n1 = *(const half8*)(gh + o + 128);
        }
        __syncthreads();
        f32x4 a0 = {0.f, 0.f, 0.f, 0.f}, a1 = {0.f, 0.f, 0.f, 0.f};
#pragma unroll
        for (int ks = 0; ks < 8; ++ks) {
            const half8 bh = *(const half8*)&Bs[buf][m][ks * 32 + q * 8];
            a0 = __builtin_amdgcn_mfma_f32_16x16x32_f16(Ah[0][ks], bh, a0, 0, 0, 0);
            a1 = __builtin_amdgcn_mfma_f32_16x16x32_f16(Ah[1][ks], bh, a1, 0, 0, 0);
        }
        const int code = kb + tile * 16 + m;
        const float sc2 = sq[code];
#pragma unroll
        for (int f = 0; f < 2; ++f) {
            const f32x4 a = f ? a1 : a0;
#pragma unroll
            for (int r = 0; r < 4; ++r) {
                const float d0 = fmaf(-0.001953125f, a[r], sc2);  // -2/1024: undo B scale
                if (d0 < bestv[f][r]) { bestv[f][r] = d0; bestk[f][r] = code; }
            }
        }
        __syncthreads();
        if (tile + 1 < 32) {
            *(half8*)&Bs[buf ^ 1][sc][sk * 8]       = n0;
            *(half8*)&Bs[buf ^ 1][sc][sk * 8 + 128] = n1;
        }
    }

    // cross-lane argmin over the 16 code-classes; tie -> lower k
#pragma unroll
    for (int f = 0; f < 2; ++f)
#pragma unroll
        for (int r = 0; r < 4; ++r) {
            float v = bestv[f][r];
            int   k = bestk[f][r];
#pragma unroll
            for (int d = 1; d < 16; d <<= 1) {
                const float ov = __shfl_xor(v, d);
                const int   ok = __shfl_xor(k, d);
                if (ov < v || (ov == v && ok < k)) { v = ov; k = ok; }
            }
            if (m == 0) {
                const int grow = row0 + f * 16 + q * 4 + r;
                partv[half * N_VEC + grow] = v;
                partk[half * N_VEC + grow] = k;
            }
        }
}

// ---- merge halves + histogram + loss; last block (ticket) runs finalize ----
__global__ __launch_bounds__(512) void merge_kernel(
    const float* __restrict__ partv, const int* __restrict__ partk,
    const float* __restrict__ xsq, int* __restrict__ codeG,
    int* __restrict__ counts, float* __restrict__ loss_accum,
    int* __restrict__ ticket, float* __restrict__ out)
{
    __shared__ float wsum[8];
    __shared__ int lastflag;
    const int t = threadIdx.x;
    const int n = blockIdx.x * 512 + t;
    const float v0 = partv[n];          const int k0 = partk[n];
    const float v1 = partv[N_VEC + n];  const int k1 = partk[N_VEC + n];
    const int   k = (v1 < v0) ? k1 : k0;      // tie -> half0 (lower codes)
    const float v = (v1 < v0) ? v1 : v0;
    codeG[n] = k;
    atomicAdd(&counts[k], 1);
    float lp = xsq[n] + v;                    // ||x - c||^2
#pragma unroll
    for (int off = 32; off > 0; off >>= 1) lp += __shfl_down(lp, off);
    if ((t & 63) == 0) wsum[t >> 6] = lp;
    __syncthreads();
    if (t == 0) {
        float bs = 0.f;
#pragma unroll
        for (int i = 0; i < 8; ++i) bs += wsum[i];
        atomicAdd(loss_accum, bs);
        __threadfence();
        lastflag = (atomicAdd(ticket, 1) == 63);
    }
    __syncthreads();
    if (!lastflag) return;
    __threadfence();
    // finalize: entropy over counts + loss scalar
    float s = 0.f;
#pragma unroll
    for (int mm = 0; mm < 2; ++mm) {
        const float p = (float)atomicAdd(&counts[t + 512 * mm], 0) * (1.f / 32768.f);
        s += p * logf(p + 1e-10f);
    }
#pragma unroll
    for (int off = 32; off > 0; off >>= 1) s += __shfl_down(s, off);
    __syncthreads();
    if ((t & 63) == 0) wsum[t >> 6] = s;
    __syncthreads();
    if (t == 0) {
        float total = 0.f;
#pragma unroll
        for (int i = 0; i < 8; ++i) total += wsum[i];
        out[OUT_ELEMS]     = atomicAdd(loss_accum, 0.f) * (1.25f / 8388608.f);
        out[OUT_ELEMS + 1] = expf(-total);
    }
}

// ---- gather: out = cb[codeG[n]][c], float4 stores ----
__global__ __launch_bounds__(256) void gather_kernel(
    const float* __restrict__ cb, const int* __restrict__ codeG,
    float* __restrict__ out)
{
    const int g = (blockIdx.x * 256 + threadIdx.x) * 4;
    const int c  = (g >> 10) & 255;
    const int n  = ((g >> 18) << 10) | (g & 1023);
    const int4 k4 = *(const int4*)(codeG + n);
    float4 o;
    o.x = cb[(size_t)k4.x * 256 + c];
    o.y = cb[(size_t)k4.y * 256 + c];
    o.z = cb[(size_t)k4.z * 256 + c];
    o.w = cb[(size_t)k4.w * 256 + c];
    *(float4*)(out + g) = o;
}

extern "C" void kernel_launch(void* const* d_in, const int* in_sizes, int n_in,
                              void* d_out, int out_size, void* d_ws, size_t ws_size,
                              hipStream_t stream) {
    const float* x  = (const float*)d_in[0];
    const float* cb = (const float*)d_in[1];
    float* out = (float*)d_out;
    char* wsb = (char*)d_ws;
    int*            counts = (int*)(wsb + 0);
    float*          loss   = (float*)(wsb + 4096);
    int*            ticket = (int*)(wsb + 4100);
    float*          sq     = (float*)(wsb + 8192);
    unsigned short* chs    = (unsigned short*)(wsb + 16384);
    float*          partv  = (float*)(wsb + 540672);
    int*            partk  = (int*)(wsb + 802816);
    float*          xsq    = (float*)(wsb + 1064960);
    int*            codeG  = (int*)(wsb + 1196032);

    hipMemsetAsync(d_ws, 0, 8192, stream);
    prep_kernel<<<64, 256, 0, stream>>>(cb, chs, sq);
    argmin_mfma_kernel<<<512, 256, 0, stream>>>(x, chs, sq, partv, partk, xsq);
    merge_kernel<<<64, 512, 0, stream>>>(partv, partk, xsq, codeG, counts, loss, ticket, out);
    gather_kernel<<<8192, 256, 0, stream>>>(cb, codeG, out);
}